// Round 4
// baseline (792.873 us; speedup 1.0000x reference)
//
#include <hip/hip_runtime.h>

#define DMDL 3072
#define SEQ  2560
#define STXT 512
#define HEADS 24
#define DHD  128
#define WB9 9437184  // 3072*3072

typedef float f32x4 __attribute__((ext_vector_type(4)));
typedef __bf16 bf16x8 __attribute__((ext_vector_type(8)));
typedef unsigned short u16x4 __attribute__((ext_vector_type(4)));

static __device__ __forceinline__ unsigned short f2bf(float f) {
  unsigned u = __float_as_uint(f);
  u += 0x7fffu + ((u >> 16) & 1u);
  return (unsigned short)(u >> 16);
}

static __device__ __forceinline__ float fexp2(float x) {
  return __builtin_amdgcn_exp2f(x);
}

// async global->LDS, 16B/lane; LDS dest wave-uniform base + lane*16.
static __device__ __forceinline__ void gload16(const unsigned short* g, unsigned short* l) {
  __builtin_amdgcn_global_load_lds(
      (const __attribute__((address_space(1))) unsigned int*)g,
      (__attribute__((address_space(3))) unsigned int*)l, 16, 0, 0);
}

// ---------------------------------------------------------------------------
// f32 -> bf16 convert, grid = n/1024
// ---------------------------------------------------------------------------
__global__ __launch_bounds__(256) void convf2b_kernel(
    const float* __restrict__ src, unsigned short* __restrict__ dst) {
  const int idx4 = blockIdx.x * 256 + threadIdx.x;
  float4 v = *(const float4*)(src + (size_t)idx4 * 4);
  u16x4 b = { f2bf(v.x), f2bf(v.y), f2bf(v.z), f2bf(v.w) };
  *(u16x4*)(dst + (size_t)idx4 * 4) = b;
}

// batched weight conv: up to 3 srcs (blockIdx.y selects), each 3072x3072
__global__ __launch_bounds__(256) void convw_kernel(
    const float* __restrict__ s0, const float* __restrict__ s1,
    const float* __restrict__ s2, unsigned short* __restrict__ dst) {
  const float* src = (blockIdx.y == 0) ? s0 : (blockIdx.y == 1) ? s1 : s2;
  const size_t idx4 = (size_t)blockIdx.x * 256 + threadIdx.x;
  float4 v = *(const float4*)(src + idx4 * 4);
  u16x4 b = { f2bf(v.x), f2bf(v.y), f2bf(v.z), f2bf(v.w) };
  *(u16x4*)(dst + (size_t)blockIdx.y * WB9 + idx4 * 4) = b;
}

// ---------------------------------------------------------------------------
// GEMM core: 128x256 tile, BK=64, 512 threads (8 waves as 2Mx4N, 64x64 each).
// Double-buffered LDS; next K-tile staged (global_load_lds) at top of each
// step so loads overlap the whole compute phase; one vmcnt(0)+barrier per
// K-tile. Pre-swizzled global source + XOR-swizzled ds_read (conflict-free).
// A bf16 [M][3072] rows @row0; Bw bf16 [N][3072] rows = out cols @col0;
// C f32 ldc=3072, bias per col.
// ---------------------------------------------------------------------------
__device__ __forceinline__ void gemm_core(
    const unsigned short* __restrict__ A, const unsigned short* __restrict__ Bw,
    const float* __restrict__ bias, float* __restrict__ C,
    int row0, int col0) {
  __shared__ unsigned short sA[2][128][64];
  __shared__ unsigned short sB[2][256][64];
  const int t = threadIdx.x, w = t >> 6, l = t & 63;
  const int wm = w >> 2, wn = w & 3;
  const int l15 = l & 15, lg = l >> 4;
  f32x4 acc[4][4];
#pragma unroll
  for (int i = 0; i < 4; i++)
#pragma unroll
    for (int j = 0; j < 4; j++) acc[i][j] = (f32x4){0.f, 0.f, 0.f, 0.f};

#define STAGE_TILE(kt, buf)                                                     \
  {                                                                             \
    const int kk = (kt) << 6;                                                   \
    _Pragma("unroll")                                                           \
    for (int g = 0; g < 2; g++) {                                               \
      const int jb = (g << 3) + w;                                              \
      const int u = (jb << 6) + l;                                              \
      const int row = u >> 3, sl = u & 7;                                       \
      const int col = (sl ^ (row & 7)) << 3;                                    \
      gload16(A + (size_t)(row0 + row) * DMDL + kk + col,                       \
              &sA[buf][0][0] + (size_t)(jb << 9));                              \
    }                                                                           \
    _Pragma("unroll")                                                           \
    for (int g = 0; g < 4; g++) {                                               \
      const int jb = (g << 3) + w;                                              \
      const int u = (jb << 6) + l;                                              \
      const int row = u >> 3, sl = u & 7;                                       \
      const int col = (sl ^ (row & 7)) << 3;                                    \
      gload16(Bw + (size_t)(col0 + row) * DMDL + kk + col,                      \
              &sB[buf][0][0] + (size_t)(jb << 9));                              \
    }                                                                           \
  }

  STAGE_TILE(0, 0)
  asm volatile("s_waitcnt vmcnt(0)" ::: "memory");
  __syncthreads();

  const int NT = DMDL / 64;  // 48
  for (int kt = 0; kt < NT; kt++) {
    const int cur = kt & 1;
    if (kt + 1 < NT) STAGE_TILE(kt + 1, cur ^ 1)
    // compute from buf cur
    bf16x8 bfr[2][4], af[2][4];
#pragma unroll
    for (int kf = 0; kf < 2; kf++)
#pragma unroll
      for (int j = 0; j < 4; j++) {
        const int rb = (wn << 6) + (j << 4) + l15;
        bfr[kf][j] = *(const bf16x8*)&sB[cur][rb][(((kf << 2) + lg) ^ (rb & 7)) << 3];
      }
#pragma unroll
    for (int kf = 0; kf < 2; kf++)
#pragma unroll
      for (int i = 0; i < 4; i++) {
        const int ra = (wm << 6) + (i << 4) + l15;
        af[kf][i] = *(const bf16x8*)&sA[cur][ra][(((kf << 2) + lg) ^ (ra & 7)) << 3];
      }
    __builtin_amdgcn_s_setprio(1);
#pragma unroll
    for (int kf = 0; kf < 2; kf++)
#pragma unroll
      for (int i = 0; i < 4; i++)
#pragma unroll
        for (int j = 0; j < 4; j++)
          acc[i][j] = __builtin_amdgcn_mfma_f32_16x16x32_bf16(af[kf][i], bfr[kf][j], acc[i][j], 0, 0, 0);
    __builtin_amdgcn_s_setprio(0);
    asm volatile("s_waitcnt vmcnt(0)" ::: "memory");
    __syncthreads();
  }
#undef STAGE_TILE

#pragma unroll
  for (int i = 0; i < 4; i++)
#pragma unroll
    for (int j = 0; j < 4; j++) {
      const int col = col0 + (wn << 6) + (j << 4) + l15;
      const float bb = bias[col];
      const int rbase = row0 + (wm << 6) + (i << 4) + (lg << 2);
#pragma unroll
      for (int r2 = 0; r2 < 4; r2++)
        C[(size_t)(rbase + r2) * DMDL + col] = acc[i][j][r2] + bb;
    }
}

// Fused 3-output GEMM: Bw = w3 (3 stacked 3072x3072). grid = (M/128)*36.
__global__ __launch_bounds__(512) void gemm3_kernel(
    const unsigned short* __restrict__ A, const unsigned short* __restrict__ w3,
    const float* __restrict__ b0, const float* __restrict__ b1, const float* __restrict__ b2,
    float* __restrict__ c0, float* __restrict__ c1, float* __restrict__ c2, int M) {
  const int nwg = (M >> 7) * 36;
  const int cpx = nwg >> 3;
  const int sid = (blockIdx.x & 7) * cpx + (blockIdx.x >> 3);
  const int by = sid / 36, bxx = sid - by * 36;
  const int grp = bxx / 12, bx = bxx - grp * 12;
  const unsigned short* Bw = w3 + (size_t)grp * WB9;
  const float* bias = (grp == 0) ? b0 : (grp == 1) ? b1 : b2;
  float* C = (grp == 0) ? c0 : (grp == 1) ? c1 : c2;
  gemm_core(A, Bw, bias, C, by << 7, bx << 8);
}

// Grouped output GEMM: blocks 0..191 img (Wo), 192..239 enc (Wao). grid 240.
__global__ __launch_bounds__(512) void gemm_out_kernel(
    const unsigned short* __restrict__ attnbf, const unsigned short* __restrict__ w3,
    const float* __restrict__ bo, const float* __restrict__ bao,
    float* __restrict__ out) {
  const int sid = (blockIdx.x & 7) * 30 + (blockIdx.x >> 3);
  if (sid < 192) {
    const int by = sid / 12, bx = sid - by * 12;
    gemm_core(attnbf + (size_t)STXT * DMDL, w3, bo, out, by << 7, bx << 8);
  } else {
    const int s2 = sid - 192;
    const int by = s2 / 12, bx = s2 - by * 12;
    gemm_core(attnbf, w3 + WB9, bao, out + (size_t)2048 * DMDL, by << 7, bx << 8);
  }
}

// ---------------------------------------------------------------------------
// LoRA down (q and k batched via blockIdx.y): tmp[M][16]
// ---------------------------------------------------------------------------
__global__ __launch_bounds__(256) void lora_down2_kernel(
    const float* __restrict__ q0, const float* __restrict__ k0,
    const float* __restrict__ qad, const float* __restrict__ kad,
    float* __restrict__ tmpq, float* __restrict__ tmpk) {
  const int t = threadIdx.x, w = t >> 6, l = t & 63;
  const int m = blockIdx.x;
  const float* X = blockIdx.y ? k0 : q0;
  const float* dwn = blockIdx.y ? kad : qad;
  float* tmp = blockIdx.y ? tmpk : tmpq;
  const float* x = X + (size_t)m * DMDL;
  float acc[16];
#pragma unroll
  for (int r = 0; r < 16; r++) acc[r] = 0.f;
  for (int k = t; k < DMDL; k += 256) {
    float xv = x[k];
#pragma unroll
    for (int r = 0; r < 16; r++) acc[r] += xv * dwn[r * DMDL + k];
  }
#pragma unroll
  for (int off = 1; off < 64; off <<= 1)
#pragma unroll
    for (int r = 0; r < 16; r++) acc[r] += __shfl_xor(acc[r], off);
  __shared__ float red[4][16];
  if (l == 0)
#pragma unroll
    for (int r = 0; r < 16; r++) red[w][r] = acc[r];
  __syncthreads();
  if (t < 16) tmp[(size_t)m * 16 + t] = red[0][t] + red[1][t] + red[2][t] + red[3][t];
}

// ---------------------------------------------------------------------------
// Pack q,k: (+LoRA-up for image rows) + RMSNorm + RoPE + scale + bf16
// Q scale includes log2e fold: 1/sqrt(128)*log2(e).
// grid (SEQ/4, HEADS, 2), wave per s.
// ---------------------------------------------------------------------------
#define QSCALE 0.12751743f
__global__ __launch_bounds__(256) void pack_kernel(
    const float* __restrict__ q0, const float* __restrict__ k0,
    const float* __restrict__ eq, const float* __restrict__ ek,
    const float* __restrict__ tmpq, const float* __restrict__ tmpk,
    const float* __restrict__ qau, const float* __restrict__ kau,
    const float* __restrict__ nq, const float* __restrict__ nk,
    const float* __restrict__ naq, const float* __restrict__ nak,
    const float* __restrict__ rc, const float* __restrict__ rsn,
    unsigned short* __restrict__ Qp, unsigned short* __restrict__ Kp) {
  const int t = threadIdx.x, w = t >> 6, l = t & 63;
  const int s = blockIdx.x * 4 + w;
  const int h = blockIdx.y;
  const int which = blockIdx.z;
  const int n = h * DHD + 2 * l;
  float2 x;
  const float* nw;
  if (s < STXT) {
    x = *(const float2*)(((which == 0) ? eq : ek) + (size_t)s * DMDL + n);
    nw = (which == 0) ? naq : nak;
  } else {
    x = *(const float2*)(((which == 0) ? q0 : k0) + (size_t)(s - STXT) * DMDL + n);
    nw = (which == 0) ? nq : nk;
    const float* tv = ((which == 0) ? tmpq : tmpk) + (size_t)(s - STXT) * 16;
    const float* uv = ((which == 0) ? qau : kau) + (size_t)n * 16;
    float l1 = 0.f, l2 = 0.f;
#pragma unroll
    for (int r = 0; r < 16; r++) { l1 += tv[r] * uv[r]; l2 += tv[r] * uv[16 + r]; }
    x.x += l1; x.y += l2;
  }
  float ss = x.x * x.x + x.y * x.y;
#pragma unroll
  for (int off = 1; off < 64; off <<= 1) ss += __shfl_xor(ss, off);
  float inv = rsqrtf(ss * (1.f / 128.f) + 1e-6f);
  float xw1 = x.x * inv * nw[2 * l];
  float xw2 = x.y * inv * nw[2 * l + 1];
  float c1 = rc[(size_t)s * DHD + 2 * l], c2 = rc[(size_t)s * DHD + 2 * l + 1];
  float s1 = rsn[(size_t)s * DHD + 2 * l], s2 = rsn[(size_t)s * DHD + 2 * l + 1];
  float y1 = xw1 * c1 - xw2 * s1;
  float y2 = xw2 * c2 + xw1 * s2;
  if (which == 0) { y1 *= QSCALE; y2 *= QSCALE; }
  unsigned short* dst = ((which == 0) ? Qp : Kp) + ((size_t)h * SEQ + s) * DHD + 2 * l;
  unsigned pk = (unsigned)f2bf(y1) | ((unsigned)f2bf(y2) << 16);
  *(unsigned*)dst = pk;
}

// ---------------------------------------------------------------------------
// V pack transposed: Vtg[h][d][s] bf16. grid (40,24).
// ---------------------------------------------------------------------------
__global__ __launch_bounds__(256) void vpackT_kernel(
    const float* __restrict__ v0, const float* __restrict__ ev,
    unsigned short* __restrict__ Vtg) {
  __shared__ unsigned short tile[64][136];
  const int t = threadIdx.x;
  const int s0 = blockIdx.x << 6;
  const int h = blockIdx.y;
  const float* src;
  int srow;
  if (s0 < STXT) { src = ev; srow = s0; } else { src = v0; srow = s0 - STXT; }
#pragma unroll
  for (int p = 0; p < 8; p++) {
    int idx4 = (p << 8) + t;
    int r = idx4 >> 5, c4 = idx4 & 31;
    float4 v = *(const float4*)(src + (size_t)(srow + r) * DMDL + h * DHD + (c4 << 2));
    u16x4 b = { f2bf(v.x), f2bf(v.y), f2bf(v.z), f2bf(v.w) };
    *(u16x4*)&tile[r][c4 << 2] = b;
  }
  __syncthreads();
  const int d = t >> 1, sc = (t & 1) << 5;
  unsigned short outv[32];
#pragma unroll
  for (int e = 0; e < 32; e++) outv[e] = tile[sc + e][d];
  unsigned short* dst = Vtg + ((size_t)h * DHD + d) * SEQ + s0 + sc;
#pragma unroll
  for (int q = 0; q < 4; q++)
    *(uint4*)(dst + (q << 3)) = *(uint4*)&outv[q << 3];
}

// ---------------------------------------------------------------------------
// Bokeh LoRA down / up
// ---------------------------------------------------------------------------
__global__ __launch_bounds__(256) void bokeh_down_kernel(
    const float* __restrict__ bok, const float* __restrict__ kbd,
    const float* __restrict__ vbd, float* __restrict__ tkv) {
  const int t = threadIdx.x, w = t >> 6, l = t & 63;
  const int mat = blockIdx.x >> 2, j = blockIdx.x & 3;
  const float* dwn = mat ? vbd : kbd;
  const float* x = bok + (size_t)j * DMDL;
  float acc[16];
#pragma unroll
  for (int r = 0; r < 16; r++) acc[r] = 0.f;
  for (int k = t; k < DMDL; k += 256) {
    float xv = x[k];
#pragma unroll
    for (int r = 0; r < 16; r++) acc[r] += xv * dwn[r * DMDL + k];
  }
#pragma unroll
  for (int off = 1; off < 64; off <<= 1)
#pragma unroll
    for (int r = 0; r < 16; r++) acc[r] += __shfl_xor(acc[r], off);
  __shared__ float red[4][16];
  if (l == 0)
#pragma unroll
    for (int r = 0; r < 16; r++) red[w][r] = acc[r];
  __syncthreads();
  if (t < 16) tkv[(mat * 4 + j) * 16 + t] = red[0][t] + red[1][t] + red[2][t] + red[3][t];
}

__global__ __launch_bounds__(256) void bokeh_up_kernel(
    const float* __restrict__ tkv, const float* __restrict__ kbu,
    const float* __restrict__ vbu, float* __restrict__ kdvd) {
  const int idx = blockIdx.x * 256 + threadIdx.x;
  const int mat = idx / 12288, rem = idx % 12288;
  const int j = rem / DMDL, n = rem % DMDL;
  const float* up = mat ? vbu : kbu;
  const float* tv = tkv + (mat * 4 + j) * 16;
  float s = 0.f;
#pragma unroll
  for (int r = 0; r < 16; r++) s += tv[r] * up[(size_t)n * 16 + r];
  kdvd[(size_t)(mat * 4 + j) * DMDL + n] = s;
}

// ---------------------------------------------------------------------------
// Flash attention + fused bokeh cross-attn epilogue -> bf16 out.
// grid (SEQ/64, HEADS), 4 waves x 16 q-rows, KVBLK=128.
// Q pre-scaled by (1/sqrt(128))*log2e -> exp2 directly. Defer-max (THR=8).
// ---------------------------------------------------------------------------
__global__ __launch_bounds__(256) void attn_kernel(
    const unsigned short* __restrict__ Qp, const unsigned short* __restrict__ Kp,
    const unsigned short* __restrict__ Vtg, const float* __restrict__ kdvd,
    unsigned short* __restrict__ attnbf) {
  __shared__ unsigned short Klds[128][128];
  __shared__ unsigned short Vt[128][128];
  __shared__ unsigned short Plds[4][16][128];
  const int t = threadIdx.x, w = t >> 6, l = t & 63;
  const int l15 = l & 15, lg = l >> 4;
  const int h = blockIdx.y;
  const int q0r = blockIdx.x * 64;
  const unsigned short* Qh = Qp + (size_t)h * SEQ * DHD;
  const unsigned short* Kh = Kp + (size_t)h * SEQ * DHD;
  const unsigned short* Vh = Vtg + (size_t)h * DHD * SEQ;

  bf16x8 qf[4];
  {
    const unsigned short* qsrc = Qh + (size_t)(q0r + w * 16 + l15) * DHD + (lg << 3);
#pragma unroll
    for (int kf = 0; kf < 4; kf++) qf[kf] = *(const bf16x8*)(qsrc + kf * 32);
  }
  f32x4 o[8];
#pragma unroll
  for (int nc = 0; nc < 8; nc++) o[nc] = (f32x4){0.f, 0.f, 0.f, 0.f};
  float m[4] = {-1e30f, -1e30f, -1e30f, -1e30f};
  float sum[4] = {0.f, 0.f, 0.f, 0.f};

  for (int kv0 = 0; kv0 < SEQ; kv0 += 128) {
    __syncthreads();
#pragma unroll
    for (int g = 0; g < 8; g++) {
      const int jb = ((g << 2) + w) << 6;
      const int jl = jb + l;
      const int row = jl >> 4, sl = jl & 15;
      const int col = (sl ^ (row & 7)) << 3;
      gload16(Kh + (size_t)(kv0 + row) * DHD + col, ((unsigned short*)Klds) + (size_t)jb * 8);
      gload16(Vh + (size_t)row * SEQ + kv0 + col, ((unsigned short*)Vt) + (size_t)jb * 8);
    }
    asm volatile("s_waitcnt vmcnt(0)" ::: "memory");
    __syncthreads();
    // QK^T (scores already in log2 units)
    f32x4 sacc[8];
    __builtin_amdgcn_s_setprio(1);
#pragma unroll
    for (int c = 0; c < 8; c++) {
      sacc[c] = (f32x4){0.f, 0.f, 0.f, 0.f};
      const int krow = c * 16 + l15;
#pragma unroll
      for (int kf = 0; kf < 4; kf++) {
        bf16x8 kb = *(const bf16x8*)&Klds[krow][(((kf << 2) + lg) ^ (krow & 7)) << 3];
        sacc[c] = __builtin_amdgcn_mfma_f32_16x16x32_bf16(qf[kf], kb, sacc[c], 0, 0, 0);
      }
    }
    __builtin_amdgcn_s_setprio(0);
    // tile max per row
    float mxv[4];
#pragma unroll
    for (int j = 0; j < 4; j++) {
      float mx = sacc[0][j];
#pragma unroll
      for (int c = 1; c < 8; c++) mx = fmaxf(mx, sacc[c][j]);
#pragma unroll
      for (int off = 1; off < 16; off <<= 1) mx = fmaxf(mx, __shfl_xor(mx, off));
      mxv[j] = mx;
    }
    int ok = 1;
#pragma unroll
    for (int j = 0; j < 4; j++) ok &= (mxv[j] <= m[j] + 8.f);
    const bool skip = __all(ok);
    float sc4[4];
#pragma unroll
    for (int j = 0; j < 4; j++) {
      const float mnew = skip ? m[j] : fmaxf(m[j], mxv[j]);
      const int prow = (lg << 2) + j;
      unsigned short* pp = &Plds[w][prow][0];
      float ps = 0.f;
#pragma unroll
      for (int c = 0; c < 8; c++) {
        float pv = fexp2(sacc[c][j] - mnew);
        ps += pv;
        pp[(c * 16 + l15) ^ ((prow & 7) << 3)] = f2bf(pv);
      }
#pragma unroll
      for (int off = 1; off < 16; off <<= 1) ps += __shfl_xor(ps, off);
      if (!skip) {
        float sc = fexp2(m[j] - mnew);
        sum[j] = sum[j] * sc + ps;
        m[j] = mnew;
        sc4[j] = sc;
      } else {
        sum[j] += ps;
      }
    }
    if (!skip) {
#pragma unroll
      for (int nc = 0; nc < 8; nc++) {
        o[nc][0] *= sc4[0]; o[nc][1] *= sc4[1]; o[nc][2] *= sc4[2]; o[nc][3] *= sc4[3];
      }
    }
    // PV
    __builtin_amdgcn_s_setprio(1);
#pragma unroll
    for (int kf2 = 0; kf2 < 4; kf2++) {
      bf16x8 pa = *(const bf16x8*)&Plds[w][l15][(((kf2 << 2) + lg) ^ (l15 & 7)) << 3];
#pragma unroll
      for (int nc = 0; nc < 8; nc++) {
        const int vrow = nc * 16 + l15;
        bf16x8 vb = *(const bf16x8*)&Vt[vrow][(((kf2 << 2) + lg) ^ (vrow & 7)) << 3];
        o[nc] = __builtin_amdgcn_mfma_f32_16x16x32_bf16(pa, vb, o[nc], 0, 0, 0);
      }
    }
    __builtin_amdgcn_s_setprio(0);
  }

  // ---- epilogue: bokeh cross-attn (4 keys) + normalize + bf16 store ----
  __syncthreads();
  float* kdl = (float*)&Klds[0][0];  // [8][128] f32: kd rows 0..3, vd rows 4..7
  {
    const int j8 = t >> 5, d4 = (t & 31) << 2;
    *(float4*)&kdl[j8 * 128 + d4] = *(const float4*)(kdvd + (size_t)j8 * DMDL + h * DHD + d4);
  }
  __syncthreads();
  float q32[4][8];
#pragma unroll
  for (int kf = 0; kf < 4; kf++)
#pragma unroll
    for (int r = 0; r < 8; r++) q32[kf][r] = (float)qf[kf][r];
  float pj[4];
#pragma unroll
  for (int jb = 0; jb < 4; jb++) {
    float d = 0.f;
#pragma unroll
    for (int kf = 0; kf < 4; kf++)
#pragma unroll
      for (int r = 0; r < 8; r++)
        d += q32[kf][r] * kdl[jb * 128 + (kf << 5) + (lg << 3) + r];
    d += __shfl_xor(d, 16);
    d += __shfl_xor(d, 32);
    pj[jb] = d;  // log2-domain score for row l15
  }
  float cm = fmaxf(fmaxf(pj[0], pj[1]), fmaxf(pj[2], pj[3]));
  float cs = 0.f;
#pragma unroll
  for (int jb = 0; jb < 4; jb++) { pj[jb] = fexp2(pj[jb] - cm); cs += pj[jb]; }
  float ci = 1.f / cs;
#pragma unroll
  for (int jb = 0; jb < 4; jb++) pj[jb] *= ci;
  float* pnl = kdl + 1024 + (w << 6);  // 64 f32 per wave
  if (lg == 0) {
#pragma unroll
    for (int jb = 0; jb < 4; jb++) pnl[l15 * 4 + jb] = pj[jb];
  }
  __syncthreads();
  float rinv[4];
#pragma unroll
  for (int j = 0; j < 4; j++) rinv[j] = 1.f / sum[j];
  float pr[4][4];
#pragma unroll
  for (int j = 0; j < 4; j++)
#pragma unroll
    for (int jb = 0; jb < 4; jb++) pr[j][jb] = pnl[(((lg << 2) + j) << 2) + jb];
  const float* vdl = kdl + 512;
#pragma unroll
  for (int nc = 0; nc < 8; nc++) {
    const int col = (nc << 4) + l15;
#pragma unroll
    for (int j = 0; j < 4; j++) {
      float cam = pr[j][0] * vdl[col] + pr[j][1] * vdl[128 + col] +
                  pr[j][2] * vdl[256 + col] + pr[j][3] * vdl[384 + col];
      float outv = o[nc][j] * rinv[j] + cam;
      const int row = q0r + (w << 4) + (lg << 2) + j;
      attnbf[(size_t)row * DMDL + h * DHD + col] = f2bf(outv);
    }
  }
}

// ---------------------------------------------------------------------------
extern "C" void kernel_launch(void* const* d_in, const int* in_sizes, int n_in,
                              void* d_out, int out_size, void* d_ws, size_t ws_size,
                              hipStream_t stream) {
  (void)in_sizes; (void)n_in; (void)out_size; (void)ws_size;
  const float* hs  = (const float*)d_in[0];
  const float* enc = (const float*)d_in[1];
  const float* bok = (const float*)d_in[2];
  const float* rc  = (const float*)d_in[3];
  const float* rsn = (const float*)d_in[4];
  const float* Wq  = (const float*)d_in[5];
  const float* Wk  = (const float*)d_in[6];
  const float* Wv  = (const float*)d_in[7];
  const float* Waq = (const float*)d_in[8];
  const float* Wak = (const float*)d_in[9];
  const float* Wav = (const float*)d_in[10];
  const float* Wo  = (const float*)d_in[11];
  const float* Wao = (const float*)d_in[12];
  const float* bq  = (const float*)d_in[13];
  const float* bk  = (const float*)d_in[14];
  const float* bv  = (const float*)d_in[15];
  const float* baq = (const float*)d_in[16];
  const float* bak = (const float*)d_in[17];
  const float* bav = (const float*)d_in[18];
  const float* bo  = (const float*)d_in[19];
  const float* bao = (const float*)d_in[20];
  const float* nq  = (const float*)d_in[21];
  const float* nk  = (const float*)d_in[22];
  const float* naq = (const float*)d_in[23];
  const float* nak = (const float*)d_in[24];
  const float* kbd = (const float*)d_in[25];
  const float* vbd = (const float*)d_in[26];
  const float* qad = (const float*)d_in[27];
  const float* kad = (const float*)d_in[28];
  const float* kbu = (const float*)d_in[29];
  const float* vbu = (const float*)d_in[30];
  const float* qau = (const float*)d_in[31];
  const float* kau = (const float*)d_in[32];

  char* ws = (char*)d_ws;
  unsigned short* w3     = (unsigned short*)(ws + 0);           // 56,623,104
  unsigned short* hs_bf  = (unsigned short*)(ws + 56623104);    // 12,582,912
  unsigned short* enc_bf = (unsigned short*)(ws + 69206016);    //  3,145,728
  float* q0   = (float*)(ws + 72351744);                        // 25,165,824
  float* k0   = (float*)(ws + 97517568);                        // 25,165,824
  float* v0   = (float*)(ws + 122683392);                       // 25,165,824
  float* eq   = (float*)(ws + 147849216);                       //  6,291,456
  float* ek   = (float*)(ws + 154140672);
  float* ev   = (float*)(ws + 160432128);
  float* tmpq = (float*)(ws + 166723584);
  float* tmpk = (float*)(ws + 166854656);
  float* tkv  = (float*)(ws + 166985728);
  float* kdvd = (float*)(ws + 166986240);
  unsigned short* Qp  = (unsigned short*)(ws + 167084544);      // 15,728,640
  unsigned short* Kp  = (unsigned short*)(ws + 182813184);      // 15,728,640 -> 198,541,824
  unsigned short* Vtg = (unsigned short*)(ws + 72351744);       // alias q0 (dead after pack)
  unsigned short* attnbf = (unsigned short*)(ws + 122683392);   // alias v0 (dead after vpackT)

  float* out = (float*)d_out;  // img [2048][3072] then enc [512][3072]

  dim3 blk(256);
  dim3 blk512(512);

  convf2b_kernel<<<6144, blk, 0, stream>>>(hs, hs_bf);
  convf2b_kernel<<<1536, blk, 0, stream>>>(enc, enc_bf);
  bokeh_down_kernel<<<8, blk, 0, stream>>>(bok, kbd, vbd, tkv);
  bokeh_up_kernel<<<96, blk, 0, stream>>>(tkv, kbu, vbu, kdvd);

  convw_kernel<<<dim3(9216, 3), blk, 0, stream>>>(Wq, Wk, Wv, w3);
  gemm3_kernel<<<576, blk512, 0, stream>>>(hs_bf, w3, bq, bk, bv, q0, k0, v0, 2048);
  convw_kernel<<<dim3(9216, 3), blk, 0, stream>>>(Waq, Wak, Wav, w3);
  gemm3_kernel<<<144, blk512, 0, stream>>>(enc_bf, w3, baq, bak, bav, eq, ek, ev, 512);

  lora_down2_kernel<<<dim3(2048, 2), blk, 0, stream>>>(q0, k0, qad, kad, tmpq, tmpk);

  pack_kernel<<<dim3(SEQ / 4, HEADS, 2), blk, 0, stream>>>(
      q0, k0, eq, ek, tmpq, tmpk, qau, kau, nq, nk, naq, nak, rc, rsn, Qp, Kp);
  vpackT_kernel<<<dim3(SEQ / 64, HEADS), blk, 0, stream>>>(v0, ev, Vtg);

  attn_kernel<<<dim3(SEQ / 64, HEADS), blk, 0, stream>>>(Qp, Kp, Vtg, kdvd, attnbf);

  convw_kernel<<<dim3(9216, 2), blk, 0, stream>>>(Wo, Wao, Wao, w3);
  gemm_out_kernel<<<240, blk512, 0, stream>>>(attnbf, w3, bo, bao, out);
}

// Round 5
// 714.366 us; speedup vs baseline: 1.1099x; 1.1099x over previous
//
#include <hip/hip_runtime.h>

#define DMDL 3072
#define SEQ  2560
#define STXT 512
#define HEADS 24
#define DHD  128
#define WB9 9437184  // 3072*3072

typedef float f32x4 __attribute__((ext_vector_type(4)));
typedef __bf16 bf16x8 __attribute__((ext_vector_type(8)));
typedef unsigned short u16x4 __attribute__((ext_vector_type(4)));

static __device__ __forceinline__ unsigned short f2bf(float f) {
  unsigned u = __float_as_uint(f);
  u += 0x7fffu + ((u >> 16) & 1u);
  return (unsigned short)(u >> 16);
}

static __device__ __forceinline__ float fexp2(float x) {
  return __builtin_amdgcn_exp2f(x);
}

// async global->LDS, 16B/lane; LDS dest wave-uniform base + lane*16.
static __device__ __forceinline__ void gload16(const unsigned short* g, unsigned short* l) {
  __builtin_amdgcn_global_load_lds(
      (const __attribute__((address_space(1))) unsigned int*)g,
      (__attribute__((address_space(3))) unsigned int*)l, 16, 0, 0);
}

// ---------------------------------------------------------------------------
// f32 -> bf16 convert, grid = n/1024
// ---------------------------------------------------------------------------
__global__ __launch_bounds__(256) void convf2b_kernel(
    const float* __restrict__ src, unsigned short* __restrict__ dst) {
  const int idx4 = blockIdx.x * 256 + threadIdx.x;
  float4 v = *(const float4*)(src + (size_t)idx4 * 4);
  u16x4 b = { f2bf(v.x), f2bf(v.y), f2bf(v.z), f2bf(v.w) };
  *(u16x4*)(dst + (size_t)idx4 * 4) = b;
}

// batched weight conv: up to 3 srcs (blockIdx.y selects), each 3072x3072
__global__ __launch_bounds__(256) void convw_kernel(
    const float* __restrict__ s0, const float* __restrict__ s1,
    const float* __restrict__ s2, unsigned short* __restrict__ dst) {
  const float* src = (blockIdx.y == 0) ? s0 : (blockIdx.y == 1) ? s1 : s2;
  const size_t idx4 = (size_t)blockIdx.x * 256 + threadIdx.x;
  float4 v = *(const float4*)(src + idx4 * 4);
  u16x4 b = { f2bf(v.x), f2bf(v.y), f2bf(v.z), f2bf(v.w) };
  *(u16x4*)(dst + (size_t)blockIdx.y * WB9 + idx4 * 4) = b;
}

// ---------------------------------------------------------------------------
// Shared GEMM body (R2-proven): C[128@row0][128@col0] over K=3072.
// 4 waves (2x2 of 64x64), BK=64, global_load_lds with pre-swizzled source,
// XOR-swizzled conflict-free ds_read.
// ---------------------------------------------------------------------------
__device__ __forceinline__ void gemm_body(
    const unsigned short* __restrict__ A, const unsigned short* __restrict__ Bw,
    const float* __restrict__ bias, float* __restrict__ C,
    int row0, int col0) {
  __shared__ unsigned short Al[128][64];
  __shared__ unsigned short Bl[128][64];
  const int t = threadIdx.x, w = t >> 6, l = t & 63;
  const int wr = (w >> 1) << 6, wc = (w & 1) << 6;
  const int l15 = l & 15, lg = l >> 4;
  f32x4 acc[4][4];
#pragma unroll
  for (int i = 0; i < 4; i++)
#pragma unroll
    for (int j = 0; j < 4; j++) acc[i][j] = (f32x4){0.f, 0.f, 0.f, 0.f};

  for (int k0 = 0; k0 < DMDL; k0 += 64) {
    __syncthreads();
#pragma unroll
    for (int g = 0; g < 4; g++) {
      const int jb = ((w << 2) + g) << 6;
      const int jl = jb + l;
      const int row = jl >> 3, sl = jl & 7;
      const int col = ((sl ^ (row & 7)) << 3);
      gload16(A  + (size_t)(row0 + row) * DMDL + k0 + col, ((unsigned short*)Al) + (size_t)jb * 8);
      gload16(Bw + (size_t)(col0 + row) * DMDL + k0 + col, ((unsigned short*)Bl) + (size_t)jb * 8);
    }
    asm volatile("s_waitcnt vmcnt(0)" ::: "memory");
    __syncthreads();
#pragma unroll
    for (int kf = 0; kf < 2; kf++) {
      bf16x8 af[4], bfr[4];
#pragma unroll
      for (int i = 0; i < 4; i++) {
        const int ra = wr + (i << 4) + l15;
        af[i]  = *(const bf16x8*)&Al[ra][(((kf << 2) + lg) ^ (ra & 7)) << 3];
        const int rb = wc + (i << 4) + l15;
        bfr[i] = *(const bf16x8*)&Bl[rb][(((kf << 2) + lg) ^ (rb & 7)) << 3];
      }
      __builtin_amdgcn_s_setprio(1);
#pragma unroll
      for (int i = 0; i < 4; i++)
#pragma unroll
        for (int j = 0; j < 4; j++)
          acc[i][j] = __builtin_amdgcn_mfma_f32_16x16x32_bf16(af[i], bfr[j], acc[i][j], 0, 0, 0);
      __builtin_amdgcn_s_setprio(0);
    }
  }
#pragma unroll
  for (int i = 0; i < 4; i++)
#pragma unroll
    for (int j = 0; j < 4; j++) {
      const int col = col0 + wc + (j << 4) + l15;
      const float bb = bias[col];
      const int rbase = row0 + wr + (i << 4) + (lg << 2);
#pragma unroll
      for (int r2 = 0; r2 < 4; r2++)
        C[(size_t)(rbase + r2) * DMDL + col] = acc[i][j][r2] + bb;
    }
}

// Fused 3-output GEMM, COL-MAJOR XCD chunking (each XCD owns a contiguous
// column-panel range -> W fetched ~once chip-wide; A cycles, but A is small).
// grid = (M/128)*72.
__global__ __launch_bounds__(256) void gemm3_kernel(
    const unsigned short* __restrict__ A, const unsigned short* __restrict__ w3,
    const float* __restrict__ b0, const float* __restrict__ b1, const float* __restrict__ b2,
    float* __restrict__ c0, float* __restrict__ c1, float* __restrict__ c2, int M) {
  const int nM = M >> 7;
  const int nwg = nM * 72;
  const int cpx = nwg >> 3;
  const int sid = (blockIdx.x & 7) * cpx + (blockIdx.x >> 3);
  const int bxx = sid / nM, by = sid - bxx * nM;  // col-major
  const int grp = bxx / 24, bx = bxx - grp * 24;
  const unsigned short* Bw = w3 + (size_t)grp * WB9;
  const float* bias = (grp == 0) ? b0 : (grp == 1) ? b1 : b2;
  float* C = (grp == 0) ? c0 : (grp == 1) ? c1 : c2;
  gemm_body(A, Bw, bias, C, by << 7, bx << 7);
}

// Grouped output GEMM, col-major chunking: sids 0..383 img (Wo), 384..479 enc.
__global__ __launch_bounds__(256) void gemm_out_kernel(
    const unsigned short* __restrict__ attnbf, const unsigned short* __restrict__ w3,
    const float* __restrict__ bo, const float* __restrict__ bao,
    float* __restrict__ out) {
  const int sid = (blockIdx.x & 7) * 60 + (blockIdx.x >> 3);
  if (sid < 384) {
    const int bx = sid >> 4, by = sid & 15;  // col-major
    gemm_body(attnbf + (size_t)STXT * DMDL, w3, bo, out, by << 7, bx << 7);
  } else {
    const int s2 = sid - 384;
    const int bx = s2 >> 2, by = s2 & 3;
    gemm_body(attnbf, w3 + WB9, bao, out + (size_t)2048 * DMDL, by << 7, bx << 7);
  }
}

// ---------------------------------------------------------------------------
// LoRA down (q and k batched via blockIdx.y): tmp[M][16]
// ---------------------------------------------------------------------------
__global__ __launch_bounds__(256) void lora_down2_kernel(
    const float* __restrict__ q0, const float* __restrict__ k0,
    const float* __restrict__ qad, const float* __restrict__ kad,
    float* __restrict__ tmpq, float* __restrict__ tmpk) {
  const int t = threadIdx.x, w = t >> 6, l = t & 63;
  const int m = blockIdx.x;
  const float* X = blockIdx.y ? k0 : q0;
  const float* dwn = blockIdx.y ? kad : qad;
  float* tmp = blockIdx.y ? tmpk : tmpq;
  const float* x = X + (size_t)m * DMDL;
  float acc[16];
#pragma unroll
  for (int r = 0; r < 16; r++) acc[r] = 0.f;
  for (int k = t; k < DMDL; k += 256) {
    float xv = x[k];
#pragma unroll
    for (int r = 0; r < 16; r++) acc[r] += xv * dwn[r * DMDL + k];
  }
#pragma unroll
  for (int off = 1; off < 64; off <<= 1)
#pragma unroll
    for (int r = 0; r < 16; r++) acc[r] += __shfl_xor(acc[r], off);
  __shared__ float red[4][16];
  if (l == 0)
#pragma unroll
    for (int r = 0; r < 16; r++) red[w][r] = acc[r];
  __syncthreads();
  if (t < 16) tmp[(size_t)m * 16 + t] = red[0][t] + red[1][t] + red[2][t] + red[3][t];
}

// ---------------------------------------------------------------------------
// Pack q,k: (+LoRA-up for image rows) + RMSNorm + RoPE + scale + bf16
// Q scale includes log2e fold: 1/sqrt(128)*log2(e).
// grid (SEQ/4, HEADS, 2), wave per s.
// ---------------------------------------------------------------------------
#define QSCALE 0.12751743f
__global__ __launch_bounds__(256) void pack_kernel(
    const float* __restrict__ q0, const float* __restrict__ k0,
    const float* __restrict__ eq, const float* __restrict__ ek,
    const float* __restrict__ tmpq, const float* __restrict__ tmpk,
    const float* __restrict__ qau, const float* __restrict__ kau,
    const float* __restrict__ nq, const float* __restrict__ nk,
    const float* __restrict__ naq, const float* __restrict__ nak,
    const float* __restrict__ rc, const float* __restrict__ rsn,
    unsigned short* __restrict__ Qp, unsigned short* __restrict__ Kp) {
  const int t = threadIdx.x, w = t >> 6, l = t & 63;
  const int s = blockIdx.x * 4 + w;
  const int h = blockIdx.y;
  const int which = blockIdx.z;
  const int n = h * DHD + 2 * l;
  float2 x;
  const float* nw;
  if (s < STXT) {
    x = *(const float2*)(((which == 0) ? eq : ek) + (size_t)s * DMDL + n);
    nw = (which == 0) ? naq : nak;
  } else {
    x = *(const float2*)(((which == 0) ? q0 : k0) + (size_t)(s - STXT) * DMDL + n);
    nw = (which == 0) ? nq : nk;
    const float* tv = ((which == 0) ? tmpq : tmpk) + (size_t)(s - STXT) * 16;
    const float* uv = ((which == 0) ? qau : kau) + (size_t)n * 16;
    float l1 = 0.f, l2 = 0.f;
#pragma unroll
    for (int r = 0; r < 16; r++) { l1 += tv[r] * uv[r]; l2 += tv[r] * uv[16 + r]; }
    x.x += l1; x.y += l2;
  }
  float ss = x.x * x.x + x.y * x.y;
#pragma unroll
  for (int off = 1; off < 64; off <<= 1) ss += __shfl_xor(ss, off);
  float inv = rsqrtf(ss * (1.f / 128.f) + 1e-6f);
  float xw1 = x.x * inv * nw[2 * l];
  float xw2 = x.y * inv * nw[2 * l + 1];
  float c1 = rc[(size_t)s * DHD + 2 * l], c2 = rc[(size_t)s * DHD + 2 * l + 1];
  float s1 = rsn[(size_t)s * DHD + 2 * l], s2 = rsn[(size_t)s * DHD + 2 * l + 1];
  float y1 = xw1 * c1 - xw2 * s1;
  float y2 = xw2 * c2 + xw1 * s2;
  if (which == 0) { y1 *= QSCALE; y2 *= QSCALE; }
  unsigned short* dst = ((which == 0) ? Qp : Kp) + ((size_t)h * SEQ + s) * DHD + 2 * l;
  unsigned pk = (unsigned)f2bf(y1) | ((unsigned)f2bf(y2) << 16);
  *(unsigned*)dst = pk;
}

// ---------------------------------------------------------------------------
// V pack transposed: Vtg[h][d][s] bf16. grid (40,24).
// ---------------------------------------------------------------------------
__global__ __launch_bounds__(256) void vpackT_kernel(
    const float* __restrict__ v0, const float* __restrict__ ev,
    unsigned short* __restrict__ Vtg) {
  __shared__ unsigned short tile[64][136];
  const int t = threadIdx.x;
  const int s0 = blockIdx.x << 6;
  const int h = blockIdx.y;
  const float* src;
  int srow;
  if (s0 < STXT) { src = ev; srow = s0; } else { src = v0; srow = s0 - STXT; }
#pragma unroll
  for (int p = 0; p < 8; p++) {
    int idx4 = (p << 8) + t;
    int r = idx4 >> 5, c4 = idx4 & 31;
    float4 v = *(const float4*)(src + (size_t)(srow + r) * DMDL + h * DHD + (c4 << 2));
    u16x4 b = { f2bf(v.x), f2bf(v.y), f2bf(v.z), f2bf(v.w) };
    *(u16x4*)&tile[r][c4 << 2] = b;
  }
  __syncthreads();
  const int d = t >> 1, sc = (t & 1) << 5;
  unsigned short outv[32];
#pragma unroll
  for (int e = 0; e < 32; e++) outv[e] = tile[sc + e][d];
  unsigned short* dst = Vtg + ((size_t)h * DHD + d) * SEQ + s0 + sc;
#pragma unroll
  for (int q = 0; q < 4; q++)
    *(uint4*)(dst + (q << 3)) = *(uint4*)&outv[q << 3];
}

// ---------------------------------------------------------------------------
// Bokeh LoRA down / up
// ---------------------------------------------------------------------------
__global__ __launch_bounds__(256) void bokeh_down_kernel(
    const float* __restrict__ bok, const float* __restrict__ kbd,
    const float* __restrict__ vbd, float* __restrict__ tkv) {
  const int t = threadIdx.x, w = t >> 6, l = t & 63;
  const int mat = blockIdx.x >> 2, j = blockIdx.x & 3;
  const float* dwn = mat ? vbd : kbd;
  const float* x = bok + (size_t)j * DMDL;
  float acc[16];
#pragma unroll
  for (int r = 0; r < 16; r++) acc[r] = 0.f;
  for (int k = t; k < DMDL; k += 256) {
    float xv = x[k];
#pragma unroll
    for (int r = 0; r < 16; r++) acc[r] += xv * dwn[r * DMDL + k];
  }
#pragma unroll
  for (int off = 1; off < 64; off <<= 1)
#pragma unroll
    for (int r = 0; r < 16; r++) acc[r] += __shfl_xor(acc[r], off);
  __shared__ float red[4][16];
  if (l == 0)
#pragma unroll
    for (int r = 0; r < 16; r++) red[w][r] = acc[r];
  __syncthreads();
  if (t < 16) tkv[(mat * 4 + j) * 16 + t] = red[0][t] + red[1][t] + red[2][t] + red[3][t];
}

__global__ __launch_bounds__(256) void bokeh_up_kernel(
    const float* __restrict__ tkv, const float* __restrict__ kbu,
    const float* __restrict__ vbu, float* __restrict__ kdvd) {
  const int idx = blockIdx.x * 256 + threadIdx.x;
  const int mat = idx / 12288, rem = idx % 12288;
  const int j = rem / DMDL, n = rem % DMDL;
  const float* up = mat ? vbu : kbu;
  const float* tv = tkv + (mat * 4 + j) * 16;
  float s = 0.f;
#pragma unroll
  for (int r = 0; r < 16; r++) s += tv[r] * up[(size_t)n * 16 + r];
  kdvd[(size_t)(mat * 4 + j) * DMDL + n] = s;
}

// ---------------------------------------------------------------------------
// Flash attention + fused bokeh cross-attn epilogue -> bf16 out.
// grid (SEQ/64, HEADS), 4 waves x 16 q-rows, KVBLK=128.
// Q pre-scaled by (1/sqrt(128))*log2e -> exp2 directly. Defer-max (THR=8).
// ---------------------------------------------------------------------------
__global__ __launch_bounds__(256) void attn_kernel(
    const unsigned short* __restrict__ Qp, const unsigned short* __restrict__ Kp,
    const unsigned short* __restrict__ Vtg, const float* __restrict__ kdvd,
    unsigned short* __restrict__ attnbf) {
  __shared__ unsigned short Klds[128][128];
  __shared__ unsigned short Vt[128][128];
  __shared__ unsigned short Plds[4][16][128];
  const int t = threadIdx.x, w = t >> 6, l = t & 63;
  const int l15 = l & 15, lg = l >> 4;
  const int h = blockIdx.y;
  const int q0r = blockIdx.x * 64;
  const unsigned short* Qh = Qp + (size_t)h * SEQ * DHD;
  const unsigned short* Kh = Kp + (size_t)h * SEQ * DHD;
  const unsigned short* Vh = Vtg + (size_t)h * DHD * SEQ;

  bf16x8 qf[4];
  {
    const unsigned short* qsrc = Qh + (size_t)(q0r + w * 16 + l15) * DHD + (lg << 3);
#pragma unroll
    for (int kf = 0; kf < 4; kf++) qf[kf] = *(const bf16x8*)(qsrc + kf * 32);
  }
  f32x4 o[8];
#pragma unroll
  for (int nc = 0; nc < 8; nc++) o[nc] = (f32x4){0.f, 0.f, 0.f, 0.f};
  float m[4] = {-1e30f, -1e30f, -1e30f, -1e30f};
  float sum[4] = {0.f, 0.f, 0.f, 0.f};

  for (int kv0 = 0; kv0 < SEQ; kv0 += 128) {
    __syncthreads();
#pragma unroll
    for (int g = 0; g < 8; g++) {
      const int jb = ((g << 2) + w) << 6;
      const int jl = jb + l;
      const int row = jl >> 4, sl = jl & 15;
      const int col = (sl ^ (row & 7)) << 3;
      gload16(Kh + (size_t)(kv0 + row) * DHD + col, ((unsigned short*)Klds) + (size_t)jb * 8);
      gload16(Vh + (size_t)row * SEQ + kv0 + col, ((unsigned short*)Vt) + (size_t)jb * 8);
    }
    asm volatile("s_waitcnt vmcnt(0)" ::: "memory");
    __syncthreads();
    // QK^T (scores already in log2 units)
    f32x4 sacc[8];
    __builtin_amdgcn_s_setprio(1);
#pragma unroll
    for (int c = 0; c < 8; c++) {
      sacc[c] = (f32x4){0.f, 0.f, 0.f, 0.f};
      const int krow = c * 16 + l15;
#pragma unroll
      for (int kf = 0; kf < 4; kf++) {
        bf16x8 kb = *(const bf16x8*)&Klds[krow][(((kf << 2) + lg) ^ (krow & 7)) << 3];
        sacc[c] = __builtin_amdgcn_mfma_f32_16x16x32_bf16(qf[kf], kb, sacc[c], 0, 0, 0);
      }
    }
    __builtin_amdgcn_s_setprio(0);
    // tile max per row
    float mxv[4];
#pragma unroll
    for (int j = 0; j < 4; j++) {
      float mx = sacc[0][j];
#pragma unroll
      for (int c = 1; c < 8; c++) mx = fmaxf(mx, sacc[c][j]);
#pragma unroll
      for (int off = 1; off < 16; off <<= 1) mx = fmaxf(mx, __shfl_xor(mx, off));
      mxv[j] = mx;
    }
    int ok = 1;
#pragma unroll
    for (int j = 0; j < 4; j++) ok &= (mxv[j] <= m[j] + 8.f);
    const bool skip = __all(ok);
    float sc4[4];
#pragma unroll
    for (int j = 0; j < 4; j++) {
      const float mnew = skip ? m[j] : fmaxf(m[j], mxv[j]);
      const int prow = (lg << 2) + j;
      unsigned short* pp = &Plds[w][prow][0];
      float ps = 0.f;
#pragma unroll
      for (int c = 0; c < 8; c++) {
        float pv = fexp2(sacc[c][j] - mnew);
        ps += pv;
        pp[(c * 16 + l15) ^ ((prow & 7) << 3)] = f2bf(pv);
      }
#pragma unroll
      for (int off = 1; off < 16; off <<= 1) ps += __shfl_xor(ps, off);
      if (!skip) {
        float sc = fexp2(m[j] - mnew);
        sum[j] = sum[j] * sc + ps;
        m[j] = mnew;
        sc4[j] = sc;
      } else {
        sum[j] += ps;
      }
    }
    if (!skip) {
#pragma unroll
      for (int nc = 0; nc < 8; nc++) {
        o[nc][0] *= sc4[0]; o[nc][1] *= sc4[1]; o[nc][2] *= sc4[2]; o[nc][3] *= sc4[3];
      }
    }
    // PV
    __builtin_amdgcn_s_setprio(1);
#pragma unroll
    for (int kf2 = 0; kf2 < 4; kf2++) {
      bf16x8 pa = *(const bf16x8*)&Plds[w][l15][(((kf2 << 2) + lg) ^ (l15 & 7)) << 3];
#pragma unroll
      for (int nc = 0; nc < 8; nc++) {
        const int vrow = nc * 16 + l15;
        bf16x8 vb = *(const bf16x8*)&Vt[vrow][(((kf2 << 2) + lg) ^ (vrow & 7)) << 3];
        o[nc] = __builtin_amdgcn_mfma_f32_16x16x32_bf16(pa, vb, o[nc], 0, 0, 0);
      }
    }
    __builtin_amdgcn_s_setprio(0);
  }

  // ---- epilogue: bokeh cross-attn (4 keys) + normalize + bf16 store ----
  __syncthreads();
  float* kdl = (float*)&Klds[0][0];  // [8][128] f32: kd rows 0..3, vd rows 4..7
  {
    const int j8 = t >> 5, d4 = (t & 31) << 2;
    *(float4*)&kdl[j8 * 128 + d4] = *(const float4*)(kdvd + (size_t)j8 * DMDL + h * DHD + d4);
  }
  __syncthreads();
  float q32[4][8];
#pragma unroll
  for (int kf = 0; kf < 4; kf++)
#pragma unroll
    for (int r = 0; r < 8; r++) q32[kf][r] = (float)qf[kf][r];
  float pj[4];
#pragma unroll
  for (int jb = 0; jb < 4; jb++) {
    float d = 0.f;
#pragma unroll
    for (int kf = 0; kf < 4; kf++)
#pragma unroll
      for (int r = 0; r < 8; r++)
        d += q32[kf][r] * kdl[jb * 128 + (kf << 5) + (lg << 3) + r];
    d += __shfl_xor(d, 16);
    d += __shfl_xor(d, 32);
    pj[jb] = d;  // log2-domain score for row l15
  }
  float cm = fmaxf(fmaxf(pj[0], pj[1]), fmaxf(pj[2], pj[3]));
  float cs = 0.f;
#pragma unroll
  for (int jb = 0; jb < 4; jb++) { pj[jb] = fexp2(pj[jb] - cm); cs += pj[jb]; }
  float ci = 1.f / cs;
#pragma unroll
  for (int jb = 0; jb < 4; jb++) pj[jb] *= ci;
  float* pnl = kdl + 1024 + (w << 6);  // 64 f32 per wave
  if (lg == 0) {
#pragma unroll
    for (int jb = 0; jb < 4; jb++) pnl[l15 * 4 + jb] = pj[jb];
  }
  __syncthreads();
  float rinv[4];
#pragma unroll
  for (int j = 0; j < 4; j++) rinv[j] = 1.f / sum[j];
  float pr[4][4];
#pragma unroll
  for (int j = 0; j < 4; j++)
#pragma unroll
    for (int jb = 0; jb < 4; jb++) pr[j][jb] = pnl[(((lg << 2) + j) << 2) + jb];
  const float* vdl = kdl + 512;
#pragma unroll
  for (int nc = 0; nc < 8; nc++) {
    const int col = (nc << 4) + l15;
#pragma unroll
    for (int j = 0; j < 4; j++) {
      float cam = pr[j][0] * vdl[col] + pr[j][1] * vdl[128 + col] +
                  pr[j][2] * vdl[256 + col] + pr[j][3] * vdl[384 + col];
      float outv = o[nc][j] * rinv[j] + cam;
      const int row = q0r + (w << 4) + (lg << 2) + j;
      attnbf[(size_t)row * DMDL + h * DHD + col] = f2bf(outv);
    }
  }
}

// ---------------------------------------------------------------------------
extern "C" void kernel_launch(void* const* d_in, const int* in_sizes, int n_in,
                              void* d_out, int out_size, void* d_ws, size_t ws_size,
                              hipStream_t stream) {
  (void)in_sizes; (void)n_in; (void)out_size; (void)ws_size;
  const float* hs  = (const float*)d_in[0];
  const float* enc = (const float*)d_in[1];
  const float* bok = (const float*)d_in[2];
  const float* rc  = (const float*)d_in[3];
  const float* rsn = (const float*)d_in[4];
  const float* Wq  = (const float*)d_in[5];
  const float* Wk  = (const float*)d_in[6];
  const float* Wv  = (const float*)d_in[7];
  const float* Waq = (const float*)d_in[8];
  const float* Wak = (const float*)d_in[9];
  const float* Wav = (const float*)d_in[10];
  const float* Wo  = (const float*)d_in[11];
  const float* Wao = (const float*)d_in[12];
  const float* bq  = (const float*)d_in[13];
  const float* bk  = (const float*)d_in[14];
  const float* bv  = (const float*)d_in[15];
  const float* baq = (const float*)d_in[16];
  const float* bak = (const float*)d_in[17];
  const float* bav = (const float*)d_in[18];
  const float* bo  = (const float*)d_in[19];
  const float* bao = (const float*)d_in[20];
  const float* nq  = (const float*)d_in[21];
  const float* nk  = (const float*)d_in[22];
  const float* naq = (const float*)d_in[23];
  const float* nak = (const float*)d_in[24];
  const float* kbd = (const float*)d_in[25];
  const float* vbd = (const float*)d_in[26];
  const float* qad = (const float*)d_in[27];
  const float* kad = (const float*)d_in[28];
  const float* kbu = (const float*)d_in[29];
  const float* vbu = (const float*)d_in[30];
  const float* qau = (const float*)d_in[31];
  const float* kau = (const float*)d_in[32];

  char* ws = (char*)d_ws;
  unsigned short* w3     = (unsigned short*)(ws + 0);           // 56,623,104
  unsigned short* hs_bf  = (unsigned short*)(ws + 56623104);    // 12,582,912
  unsigned short* enc_bf = (unsigned short*)(ws + 69206016);    //  3,145,728
  float* q0   = (float*)(ws + 72351744);                        // 25,165,824
  float* k0   = (float*)(ws + 97517568);                        // 25,165,824
  float* v0   = (float*)(ws + 122683392);                       // 25,165,824
  float* eq   = (float*)(ws + 147849216);                       //  6,291,456
  float* ek   = (float*)(ws + 154140672);
  float* ev   = (float*)(ws + 160432128);
  float* tmpq = (float*)(ws + 166723584);
  float* tmpk = (float*)(ws + 166854656);
  float* tkv  = (float*)(ws + 166985728);
  float* kdvd = (float*)(ws + 166986240);
  unsigned short* Qp  = (unsigned short*)(ws + 167084544);      // 15,728,640
  unsigned short* Kp  = (unsigned short*)(ws + 182813184);      // 15,728,640 -> 198,541,824
  unsigned short* Vtg = (unsigned short*)(ws + 72351744);       // alias q0 (dead after pack)
  unsigned short* attnbf = (unsigned short*)(ws + 122683392);   // alias v0 (dead after vpackT)

  float* out = (float*)d_out;  // img [2048][3072] then enc [512][3072]

  dim3 blk(256);

  convf2b_kernel<<<6144, blk, 0, stream>>>(hs, hs_bf);
  convf2b_kernel<<<1536, blk, 0, stream>>>(enc, enc_bf);
  bokeh_down_kernel<<<8, blk, 0, stream>>>(bok, kbd, vbd, tkv);
  bokeh_up_kernel<<<96, blk, 0, stream>>>(tkv, kbu, vbu, kdvd);

  convw_kernel<<<dim3(9216, 3), blk, 0, stream>>>(Wq, Wk, Wv, w3);
  gemm3_kernel<<<1152, blk, 0, stream>>>(hs_bf, w3, bq, bk, bv, q0, k0, v0, 2048);
  convw_kernel<<<dim3(9216, 3), blk, 0, stream>>>(Waq, Wak, Wav, w3);
  gemm3_kernel<<<288, blk, 0, stream>>>(enc_bf, w3, baq, bak, bav, eq, ek, ev, 512);

  lora_down2_kernel<<<dim3(2048, 2), blk, 0, stream>>>(q0, k0, qad, kad, tmpq, tmpk);

  pack_kernel<<<dim3(SEQ / 4, HEADS, 2), blk, 0, stream>>>(
      q0, k0, eq, ek, tmpq, tmpk, qau, kau, nq, nk, naq, nak, rc, rsn, Qp, Kp);
  vpackT_kernel<<<dim3(SEQ / 64, HEADS), blk, 0, stream>>>(v0, ev, Vtg);

  attn_kernel<<<dim3(SEQ / 64, HEADS), blk, 0, stream>>>(Qp, Kp, Vtg, kdvd, attnbf);

  convw_kernel<<<dim3(9216, 2), blk, 0, stream>>>(Wo, Wao, Wao, w3);
  gemm_out_kernel<<<480, blk, 0, stream>>>(attnbf, w3, bo, bao, out);
}

// Round 6
// 680.670 us; speedup vs baseline: 1.1648x; 1.0495x over previous
//
#include <hip/hip_runtime.h>

#define DMDL 3072
#define SEQ  2560
#define STXT 512
#define HEADS 24
#define DHD  128
#define WB9 9437184  // 3072*3072

typedef float f32x4 __attribute__((ext_vector_type(4)));
typedef __bf16 bf16x8 __attribute__((ext_vector_type(8)));
typedef unsigned short u16x4 __attribute__((ext_vector_type(4)));

static __device__ __forceinline__ unsigned short f2bf(float f) {
  unsigned u = __float_as_uint(f);
  u += 0x7fffu + ((u >> 16) & 1u);
  return (unsigned short)(u >> 16);
}

static __device__ __forceinline__ float fexp2(float x) {
  return __builtin_amdgcn_exp2f(x);
}

// async global->LDS, 16B/lane; LDS dest wave-uniform base + lane*16.
static __device__ __forceinline__ void gload16(const unsigned short* g, unsigned short* l) {
  __builtin_amdgcn_global_load_lds(
      (const __attribute__((address_space(1))) unsigned int*)g,
      (__attribute__((address_space(3))) unsigned int*)l, 16, 0, 0);
}

// ---------------------------------------------------------------------------
// f32 -> bf16 convert, grid = n/1024
// ---------------------------------------------------------------------------
__global__ __launch_bounds__(256) void convf2b_kernel(
    const float* __restrict__ src, unsigned short* __restrict__ dst) {
  const int idx4 = blockIdx.x * 256 + threadIdx.x;
  float4 v = *(const float4*)(src + (size_t)idx4 * 4);
  u16x4 b = { f2bf(v.x), f2bf(v.y), f2bf(v.z), f2bf(v.w) };
  *(u16x4*)(dst + (size_t)idx4 * 4) = b;
}

// batched weight conv: up to 3 srcs (blockIdx.y selects), each 3072x3072
__global__ __launch_bounds__(256) void convw_kernel(
    const float* __restrict__ s0, const float* __restrict__ s1,
    const float* __restrict__ s2, unsigned short* __restrict__ dst) {
  const float* src = (blockIdx.y == 0) ? s0 : (blockIdx.y == 1) ? s1 : s2;
  const size_t idx4 = (size_t)blockIdx.x * 256 + threadIdx.x;
  float4 v = *(const float4*)(src + idx4 * 4);
  u16x4 b = { f2bf(v.x), f2bf(v.y), f2bf(v.z), f2bf(v.w) };
  *(u16x4*)(dst + (size_t)blockIdx.y * WB9 + idx4 * 4) = b;
}

// ---------------------------------------------------------------------------
// Shared GEMM body (R2-proven): C[128@row0][128@col0] over K=3072.
// ---------------------------------------------------------------------------
__device__ __forceinline__ void gemm_body(
    const unsigned short* __restrict__ A, const unsigned short* __restrict__ Bw,
    const float* __restrict__ bias, float* __restrict__ C,
    int row0, int col0) {
  __shared__ unsigned short Al[128][64];
  __shared__ unsigned short Bl[128][64];
  const int t = threadIdx.x, w = t >> 6, l = t & 63;
  const int wr = (w >> 1) << 6, wc = (w & 1) << 6;
  const int l15 = l & 15, lg = l >> 4;
  f32x4 acc[4][4];
#pragma unroll
  for (int i = 0; i < 4; i++)
#pragma unroll
    for (int j = 0; j < 4; j++) acc[i][j] = (f32x4){0.f, 0.f, 0.f, 0.f};

  for (int k0 = 0; k0 < DMDL; k0 += 64) {
    __syncthreads();
#pragma unroll
    for (int g = 0; g < 4; g++) {
      const int jb = ((w << 2) + g) << 6;
      const int jl = jb + l;
      const int row = jl >> 3, sl = jl & 7;
      const int col = ((sl ^ (row & 7)) << 3);
      gload16(A  + (size_t)(row0 + row) * DMDL + k0 + col, ((unsigned short*)Al) + (size_t)jb * 8);
      gload16(Bw + (size_t)(col0 + row) * DMDL + k0 + col, ((unsigned short*)Bl) + (size_t)jb * 8);
    }
    asm volatile("s_waitcnt vmcnt(0)" ::: "memory");
    __syncthreads();
#pragma unroll
    for (int kf = 0; kf < 2; kf++) {
      bf16x8 af[4], bfr[4];
#pragma unroll
      for (int i = 0; i < 4; i++) {
        const int ra = wr + (i << 4) + l15;
        af[i]  = *(const bf16x8*)&Al[ra][(((kf << 2) + lg) ^ (ra & 7)) << 3];
        const int rb = wc + (i << 4) + l15;
        bfr[i] = *(const bf16x8*)&Bl[rb][(((kf << 2) + lg) ^ (rb & 7)) << 3];
      }
      __builtin_amdgcn_s_setprio(1);
#pragma unroll
      for (int i = 0; i < 4; i++)
#pragma unroll
        for (int j = 0; j < 4; j++)
          acc[i][j] = __builtin_amdgcn_mfma_f32_16x16x32_bf16(af[i], bfr[j], acc[i][j], 0, 0, 0);
      __builtin_amdgcn_s_setprio(0);
    }
  }
#pragma unroll
  for (int i = 0; i < 4; i++)
#pragma unroll
    for (int j = 0; j < 4; j++) {
      const int col = col0 + wc + (j << 4) + l15;
      const float bb = bias[col];
      const int rbase = row0 + wr + (i << 4) + (lg << 2);
#pragma unroll
      for (int r2 = 0; r2 < 4; r2++)
        C[(size_t)(rbase + r2) * DMDL + col] = acc[i][j][r2] + bb;
    }
}

// Fused 3-output GEMM, col-major XCD chunking. grid = (M/128)*72.
__global__ __launch_bounds__(256) void gemm3_kernel(
    const unsigned short* __restrict__ A, const unsigned short* __restrict__ w3,
    const float* __restrict__ b0, const float* __restrict__ b1, const float* __restrict__ b2,
    float* __restrict__ c0, float* __restrict__ c1, float* __restrict__ c2, int M) {
  const int nM = M >> 7;
  const int nwg = nM * 72;
  const int cpx = nwg >> 3;
  const int sid = (blockIdx.x & 7) * cpx + (blockIdx.x >> 3);
  const int bxx = sid / nM, by = sid - bxx * nM;  // col-major
  const int grp = bxx / 24, bx = bxx - grp * 24;
  const unsigned short* Bw = w3 + (size_t)grp * WB9;
  const float* bias = (grp == 0) ? b0 : (grp == 1) ? b1 : b2;
  float* C = (grp == 0) ? c0 : (grp == 1) ? c1 : c2;
  gemm_body(A, Bw, bias, C, by << 7, bx << 7);
}

// Grouped output GEMM, col-major chunking: sids 0..383 img (Wo), 384..479 enc.
__global__ __launch_bounds__(256) void gemm_out_kernel(
    const unsigned short* __restrict__ attnbf, const unsigned short* __restrict__ w3,
    const float* __restrict__ bo, const float* __restrict__ bao,
    float* __restrict__ out) {
  const int sid = (blockIdx.x & 7) * 60 + (blockIdx.x >> 3);
  if (sid < 384) {
    const int bx = sid >> 4, by = sid & 15;  // col-major
    gemm_body(attnbf + (size_t)STXT * DMDL, w3, bo, out, by << 7, bx << 7);
  } else {
    const int s2 = sid - 384;
    const int bx = s2 >> 2, by = s2 & 3;
    gemm_body(attnbf, w3 + WB9, bao, out + (size_t)2048 * DMDL, by << 7, bx << 7);
  }
}

// ---------------------------------------------------------------------------
// LoRA down (q and k batched via blockIdx.y): tmp[M][16]
// ---------------------------------------------------------------------------
__global__ __launch_bounds__(256) void lora_down2_kernel(
    const float* __restrict__ q0, const float* __restrict__ k0,
    const float* __restrict__ qad, const float* __restrict__ kad,
    float* __restrict__ tmpq, float* __restrict__ tmpk) {
  const int t = threadIdx.x, w = t >> 6, l = t & 63;
  const int m = blockIdx.x;
  const float* X = blockIdx.y ? k0 : q0;
  const float* dwn = blockIdx.y ? kad : qad;
  float* tmp = blockIdx.y ? tmpk : tmpq;
  const float* x = X + (size_t)m * DMDL;
  float acc[16];
#pragma unroll
  for (int r = 0; r < 16; r++) acc[r] = 0.f;
  for (int k = t; k < DMDL; k += 256) {
    float xv = x[k];
#pragma unroll
    for (int r = 0; r < 16; r++) acc[r] += xv * dwn[r * DMDL + k];
  }
#pragma unroll
  for (int off = 1; off < 64; off <<= 1)
#pragma unroll
    for (int r = 0; r < 16; r++) acc[r] += __shfl_xor(acc[r], off);
  __shared__ float red[4][16];
  if (l == 0)
#pragma unroll
    for (int r = 0; r < 16; r++) red[w][r] = acc[r];
  __syncthreads();
  if (t < 16) tmp[(size_t)m * 16 + t] = red[0][t] + red[1][t] + red[2][t] + red[3][t];
}

// ---------------------------------------------------------------------------
// Pack q,k: (+LoRA-up for image rows) + RMSNorm + RoPE + scale + bf16
// ---------------------------------------------------------------------------
#define QSCALE 0.12751743f
__global__ __launch_bounds__(256) void pack_kernel(
    const float* __restrict__ q0, const float* __restrict__ k0,
    const float* __restrict__ eq, const float* __restrict__ ek,
    const float* __restrict__ tmpq, const float* __restrict__ tmpk,
    const float* __restrict__ qau, const float* __restrict__ kau,
    const float* __restrict__ nq, const float* __restrict__ nk,
    const float* __restrict__ naq, const float* __restrict__ nak,
    const float* __restrict__ rc, const float* __restrict__ rsn,
    unsigned short* __restrict__ Qp, unsigned short* __restrict__ Kp) {
  const int t = threadIdx.x, w = t >> 6, l = t & 63;
  const int s = blockIdx.x * 4 + w;
  const int h = blockIdx.y;
  const int which = blockIdx.z;
  const int n = h * DHD + 2 * l;
  float2 x;
  const float* nw;
  if (s < STXT) {
    x = *(const float2*)(((which == 0) ? eq : ek) + (size_t)s * DMDL + n);
    nw = (which == 0) ? naq : nak;
  } else {
    x = *(const float2*)(((which == 0) ? q0 : k0) + (size_t)(s - STXT) * DMDL + n);
    nw = (which == 0) ? nq : nk;
    const float* tv = ((which == 0) ? tmpq : tmpk) + (size_t)(s - STXT) * 16;
    const float* uv = ((which == 0) ? qau : kau) + (size_t)n * 16;
    float l1 = 0.f, l2 = 0.f;
#pragma unroll
    for (int r = 0; r < 16; r++) { l1 += tv[r] * uv[r]; l2 += tv[r] * uv[16 + r]; }
    x.x += l1; x.y += l2;
  }
  float ss = x.x * x.x + x.y * x.y;
#pragma unroll
  for (int off = 1; off < 64; off <<= 1) ss += __shfl_xor(ss, off);
  float inv = rsqrtf(ss * (1.f / 128.f) + 1e-6f);
  float xw1 = x.x * inv * nw[2 * l];
  float xw2 = x.y * inv * nw[2 * l + 1];
  float c1 = rc[(size_t)s * DHD + 2 * l], c2 = rc[(size_t)s * DHD + 2 * l + 1];
  float s1 = rsn[(size_t)s * DHD + 2 * l], s2 = rsn[(size_t)s * DHD + 2 * l + 1];
  float y1 = xw1 * c1 - xw2 * s1;
  float y2 = xw2 * c2 + xw1 * s2;
  if (which == 0) { y1 *= QSCALE; y2 *= QSCALE; }
  unsigned short* dst = ((which == 0) ? Qp : Kp) + ((size_t)h * SEQ + s) * DHD + 2 * l;
  unsigned pk = (unsigned)f2bf(y1) | ((unsigned)f2bf(y2) << 16);
  *(unsigned*)dst = pk;
}

// ---------------------------------------------------------------------------
// V pack transposed: Vtg[h][d][s] bf16. grid (40,24).
// ---------------------------------------------------------------------------
__global__ __launch_bounds__(256) void vpackT_kernel(
    const float* __restrict__ v0, const float* __restrict__ ev,
    unsigned short* __restrict__ Vtg) {
  __shared__ unsigned short tile[64][136];
  const int t = threadIdx.x;
  const int s0 = blockIdx.x << 6;
  const int h = blockIdx.y;
  const float* src;
  int srow;
  if (s0 < STXT) { src = ev; srow = s0; } else { src = v0; srow = s0 - STXT; }
#pragma unroll
  for (int p = 0; p < 8; p++) {
    int idx4 = (p << 8) + t;
    int r = idx4 >> 5, c4 = idx4 & 31;
    float4 v = *(const float4*)(src + (size_t)(srow + r) * DMDL + h * DHD + (c4 << 2));
    u16x4 b = { f2bf(v.x), f2bf(v.y), f2bf(v.z), f2bf(v.w) };
    *(u16x4*)&tile[r][c4 << 2] = b;
  }
  __syncthreads();
  const int d = t >> 1, sc = (t & 1) << 5;
  unsigned short outv[32];
#pragma unroll
  for (int e = 0; e < 32; e++) outv[e] = tile[sc + e][d];
  unsigned short* dst = Vtg + ((size_t)h * DHD + d) * SEQ + s0 + sc;
#pragma unroll
  for (int q = 0; q < 4; q++)
    *(uint4*)(dst + (q << 3)) = *(uint4*)&outv[q << 3];
}

// ---------------------------------------------------------------------------
// Bokeh LoRA down / up
// ---------------------------------------------------------------------------
__global__ __launch_bounds__(256) void bokeh_down_kernel(
    const float* __restrict__ bok, const float* __restrict__ kbd,
    const float* __restrict__ vbd, float* __restrict__ tkv) {
  const int t = threadIdx.x, w = t >> 6, l = t & 63;
  const int mat = blockIdx.x >> 2, j = blockIdx.x & 3;
  const float* dwn = mat ? vbd : kbd;
  const float* x = bok + (size_t)j * DMDL;
  float acc[16];
#pragma unroll
  for (int r = 0; r < 16; r++) acc[r] = 0.f;
  for (int k = t; k < DMDL; k += 256) {
    float xv = x[k];
#pragma unroll
    for (int r = 0; r < 16; r++) acc[r] += xv * dwn[r * DMDL + k];
  }
#pragma unroll
  for (int off = 1; off < 64; off <<= 1)
#pragma unroll
    for (int r = 0; r < 16; r++) acc[r] += __shfl_xor(acc[r], off);
  __shared__ float red[4][16];
  if (l == 0)
#pragma unroll
    for (int r = 0; r < 16; r++) red[w][r] = acc[r];
  __syncthreads();
  if (t < 16) tkv[(mat * 4 + j) * 16 + t] = red[0][t] + red[1][t] + red[2][t] + red[3][t];
}

__global__ __launch_bounds__(256) void bokeh_up_kernel(
    const float* __restrict__ tkv, const float* __restrict__ kbu,
    const float* __restrict__ vbu, float* __restrict__ kdvd) {
  const int idx = blockIdx.x * 256 + threadIdx.x;
  const int mat = idx / 12288, rem = idx % 12288;
  const int j = rem / DMDL, n = rem % DMDL;
  const float* up = mat ? vbu : kbu;
  const float* tv = tkv + (mat * 4 + j) * 16;
  float s = 0.f;
#pragma unroll
  for (int r = 0; r < 16; r++) s += tv[r] * up[(size_t)n * 16 + r];
  kdvd[(size_t)(mat * 4 + j) * DMDL + n] = s;
}

// ---------------------------------------------------------------------------
// Flash attention, SWAPPED QK^T + in-register row softmax.
// grid (SEQ/64, HEADS), 4 waves x 16 q-rows, KVBLK=128.
// sacc = mfma(K,Q): lane holds q-row = l15, k = c*16 + lg*4 + r.
// P packed via v_cvt_pk_bf16_f32 into per-wave LDS [q=16][k=128] (slot-XOR
// swizzled), PV reads it as conflict-free ds_read_b128 A-frags.
// ---------------------------------------------------------------------------
__global__ __launch_bounds__(256) void attn_kernel(
    const unsigned short* __restrict__ Qp, const unsigned short* __restrict__ Kp,
    const unsigned short* __restrict__ Vtg, const float* __restrict__ kdvd,
    unsigned short* __restrict__ attnbf) {
  __shared__ unsigned short Klds[128][128];
  __shared__ unsigned short Vt[128][128];
  __shared__ unsigned short Pl[4][2048];  // per-wave 4KB: q=16 rows x 256B
  const int t = threadIdx.x, w = t >> 6, l = t & 63;
  const int l15 = l & 15, lg = l >> 4;
  const int h = blockIdx.y;
  const int q0r = blockIdx.x * 64;
  const unsigned short* Qh = Qp + (size_t)h * SEQ * DHD;
  const unsigned short* Kh = Kp + (size_t)h * SEQ * DHD;
  const unsigned short* Vh = Vtg + (size_t)h * DHD * SEQ;
  char* Pw = (char*)&Pl[w][0];

  bf16x8 qf[4];
  {
    const unsigned short* qsrc = Qh + (size_t)(q0r + w * 16 + l15) * DHD + (lg << 3);
#pragma unroll
    for (int kf = 0; kf < 4; kf++) qf[kf] = *(const bf16x8*)(qsrc + kf * 32);
  }
  f32x4 o[8];
#pragma unroll
  for (int nc = 0; nc < 8; nc++) o[nc] = (f32x4){0.f, 0.f, 0.f, 0.f};
  float m = -1e30f, sum = 0.f;

  for (int kv0 = 0; kv0 < SEQ; kv0 += 128) {
    __syncthreads();
#pragma unroll
    for (int g = 0; g < 8; g++) {
      const int jb = ((g << 2) + w) << 6;
      const int jl = jb + l;
      const int row = jl >> 4, sl = jl & 15;
      const int col = (sl ^ (row & 7)) << 3;
      gload16(Kh + (size_t)(kv0 + row) * DHD + col, ((unsigned short*)Klds) + (size_t)jb * 8);
      gload16(Vh + (size_t)row * SEQ + kv0 + col, ((unsigned short*)Vt) + (size_t)jb * 8);
    }
    asm volatile("s_waitcnt vmcnt(0)" ::: "memory");
    __syncthreads();
    // QK^T swapped: sacc[c][r] = score[q=l15][k = c*16 + lg*4 + r]
    f32x4 sacc[8];
    __builtin_amdgcn_s_setprio(1);
#pragma unroll
    for (int c = 0; c < 8; c++) {
      sacc[c] = (f32x4){0.f, 0.f, 0.f, 0.f};
      const int krow = c * 16 + l15;
#pragma unroll
      for (int kf = 0; kf < 4; kf++) {
        bf16x8 kb = *(const bf16x8*)&Klds[krow][(((kf << 2) + lg) ^ (krow & 7)) << 3];
        sacc[c] = __builtin_amdgcn_mfma_f32_16x16x32_bf16(kb, qf[kf], sacc[c], 0, 0, 0);
      }
    }
    __builtin_amdgcn_s_setprio(0);
    // in-lane max over 32 scores (balanced tree), then 2 cross-lane steps
    float cm[8];
#pragma unroll
    for (int c = 0; c < 8; c++)
      cm[c] = fmaxf(fmaxf(sacc[c][0], sacc[c][1]), fmaxf(sacc[c][2], sacc[c][3]));
    float pmax = fmaxf(fmaxf(fmaxf(cm[0], cm[1]), fmaxf(cm[2], cm[3])),
                       fmaxf(fmaxf(cm[4], cm[5]), fmaxf(cm[6], cm[7])));
    pmax = fmaxf(pmax, __shfl_xor(pmax, 16));
    pmax = fmaxf(pmax, __shfl_xor(pmax, 32));
    const bool skip = __all(pmax <= m + 8.f);
    const float mnew = skip ? m : fmaxf(m, pmax);
    // exp2 + pack to bf16 (cvt_pk) + b64 store into swizzled P tile
    float ps = 0.f;
#pragma unroll
    for (int c = 0; c < 8; c++) {
      float p0 = fexp2(sacc[c][0] - mnew);
      float p1 = fexp2(sacc[c][1] - mnew);
      float p2 = fexp2(sacc[c][2] - mnew);
      float p3 = fexp2(sacc[c][3] - mnew);
      ps += (p0 + p1) + (p2 + p3);
      unsigned lo, hi;
      asm("v_cvt_pk_bf16_f32 %0, %1, %2" : "=v"(lo) : "v"(p0), "v"(p1));
      asm("v_cvt_pk_bf16_f32 %0, %1, %2" : "=v"(hi) : "v"(p2), "v"(p3));
      const int byteoff = (l15 << 8) + (((((c << 1) + (lg >> 1)) ^ (l15 & 7))) << 4) + ((lg & 1) << 3);
      *(uint2*)(Pw + byteoff) = make_uint2(lo, hi);
    }
    ps += __shfl_xor(ps, 16);
    ps += __shfl_xor(ps, 32);
    if (!skip) {
      const float sc = fexp2(m - mnew);
      sum = sum * sc + ps;
      m = mnew;
      // gather per-o-row scales (o rows = lg*4 + j, scale held at lane (row))
      float s0 = __shfl(sc, (lg << 2) + 0);
      float s1 = __shfl(sc, (lg << 2) + 1);
      float s2 = __shfl(sc, (lg << 2) + 2);
      float s3 = __shfl(sc, (lg << 2) + 3);
#pragma unroll
      for (int nc = 0; nc < 8; nc++) {
        o[nc][0] *= s0; o[nc][1] *= s1; o[nc][2] *= s2; o[nc][3] *= s3;
      }
    } else {
      sum += ps;
    }
    // PV: pa from per-wave P tile (conflict-free b128), V from Vt
    __builtin_amdgcn_s_setprio(1);
#pragma unroll
    for (int kf2 = 0; kf2 < 4; kf2++) {
      bf16x8 pa = *(const bf16x8*)(Pw + (l15 << 8) + ((((kf2 << 2) + lg) ^ (l15 & 7)) << 4));
#pragma unroll
      for (int nc = 0; nc < 8; nc++) {
        const int vrow = nc * 16 + l15;
        bf16x8 vb = *(const bf16x8*)&Vt[vrow][(((kf2 << 2) + lg) ^ (vrow & 7)) << 3];
        o[nc] = __builtin_amdgcn_mfma_f32_16x16x32_bf16(pa, vb, o[nc], 0, 0, 0);
      }
    }
    __builtin_amdgcn_s_setprio(0);
  }

  // gather per-row 1/sum for o rows (lg*4 + j)
  float rinv[4];
  {
    float su0 = __shfl(sum, (lg << 2) + 0);
    float su1 = __shfl(sum, (lg << 2) + 1);
    float su2 = __shfl(sum, (lg << 2) + 2);
    float su3 = __shfl(sum, (lg << 2) + 3);
    rinv[0] = 1.f / su0; rinv[1] = 1.f / su1; rinv[2] = 1.f / su2; rinv[3] = 1.f / su3;
  }

  // ---- epilogue: bokeh cross-attn (4 keys) + normalize + bf16 store ----
  __syncthreads();
  float* kdl = (float*)&Klds[0][0];  // [8][128] f32: kd rows 0..3, vd rows 4..7
  {
    const int j8 = t >> 5, d4 = (t & 31) << 2;
    *(float4*)&kdl[j8 * 128 + d4] = *(const float4*)(kdvd + (size_t)j8 * DMDL + h * DHD + d4);
  }
  __syncthreads();
  float q32[4][8];
#pragma unroll
  for (int kf = 0; kf < 4; kf++)
#pragma unroll
    for (int r = 0; r < 8; r++) q32[kf][r] = (float)qf[kf][r];
  float pj[4];
#pragma unroll
  for (int jb = 0; jb < 4; jb++) {
    float d = 0.f;
#pragma unroll
    for (int kf = 0; kf < 4; kf++)
#pragma unroll
      for (int r = 0; r < 8; r++)
        d += q32[kf][r] * kdl[jb * 128 + (kf << 5) + (lg << 3) + r];
    d += __shfl_xor(d, 16);
    d += __shfl_xor(d, 32);
    pj[jb] = d;  // log2-domain score for row l15
  }
  float cmx = fmaxf(fmaxf(pj[0], pj[1]), fmaxf(pj[2], pj[3]));
  float cs = 0.f;
#pragma unroll
  for (int jb = 0; jb < 4; jb++) { pj[jb] = fexp2(pj[jb] - cmx); cs += pj[jb]; }
  float ci = 1.f / cs;
#pragma unroll
  for (int jb = 0; jb < 4; jb++) pj[jb] *= ci;
  float* pnl = kdl + 1024 + (w << 6);  // 64 f32 per wave
  if (lg == 0) {
#pragma unroll
    for (int jb = 0; jb < 4; jb++) pnl[l15 * 4 + jb] = pj[jb];
  }
  __syncthreads();
  float pr[4][4];
#pragma unroll
  for (int j = 0; j < 4; j++)
#pragma unroll
    for (int jb = 0; jb < 4; jb++) pr[j][jb] = pnl[(((lg << 2) + j) << 2) + jb];
  const float* vdl = kdl + 512;
#pragma unroll
  for (int nc = 0; nc < 8; nc++) {
    const int col = (nc << 4) + l15;
#pragma unroll
    for (int j = 0; j < 4; j++) {
      float cam = pr[j][0] * vdl[col] + pr[j][1] * vdl[128 + col] +
                  pr[j][2] * vdl[256 + col] + pr[j][3] * vdl[384 + col];
      float outv = o[nc][j] * rinv[j] + cam;
      const int row = q0r + (w << 4) + (lg << 2) + j;
      attnbf[(size_t)row * DMDL + h * DHD + col] = f2bf(outv);
    }
  }
}

// ---------------------------------------------------------------------------
extern "C" void kernel_launch(void* const* d_in, const int* in_sizes, int n_in,
                              void* d_out, int out_size, void* d_ws, size_t ws_size,
                              hipStream_t stream) {
  (void)in_sizes; (void)n_in; (void)out_size; (void)ws_size;
  const float* hs  = (const float*)d_in[0];
  const float* enc = (const float*)d_in[1];
  const float* bok = (const float*)d_in[2];
  const float* rc  = (const float*)d_in[3];
  const float* rsn = (const float*)d_in[4];
  const float* Wq  = (const float*)d_in[5];
  const float* Wk  = (const float*)d_in[6];
  const float* Wv  = (const float*)d_in[7];
  const float* Waq = (const float*)d_in[8];
  const float* Wak = (const float*)d_in[9];
  const float* Wav = (const float*)d_in[10];
  const float* Wo  = (const float*)d_in[11];
  const float* Wao = (const float*)d_in[12];
  const float* bq  = (const float*)d_in[13];
  const float* bk  = (const float*)d_in[14];
  const float* bv  = (const float*)d_in[15];
  const float* baq = (const float*)d_in[16];
  const float* bak = (const float*)d_in[17];
  const float* bav = (const float*)d_in[18];
  const float* bo  = (const float*)d_in[19];
  const float* bao = (const float*)d_in[20];
  const float* nq  = (const float*)d_in[21];
  const float* nk  = (const float*)d_in[22];
  const float* naq = (const float*)d_in[23];
  const float* nak = (const float*)d_in[24];
  const float* kbd = (const float*)d_in[25];
  const float* vbd = (const float*)d_in[26];
  const float* qad = (const float*)d_in[27];
  const float* kad = (const float*)d_in[28];
  const float* kbu = (const float*)d_in[29];
  const float* vbu = (const float*)d_in[30];
  const float* qau = (const float*)d_in[31];
  const float* kau = (const float*)d_in[32];

  char* ws = (char*)d_ws;
  unsigned short* w3     = (unsigned short*)(ws + 0);           // 56,623,104
  unsigned short* hs_bf  = (unsigned short*)(ws + 56623104);    // 12,582,912
  unsigned short* enc_bf = (unsigned short*)(ws + 69206016);    //  3,145,728
  float* q0   = (float*)(ws + 72351744);                        // 25,165,824
  float* k0   = (float*)(ws + 97517568);                        // 25,165,824
  float* v0   = (float*)(ws + 122683392);                       // 25,165,824
  float* eq   = (float*)(ws + 147849216);                       //  6,291,456
  float* ek   = (float*)(ws + 154140672);
  float* ev   = (float*)(ws + 160432128);
  float* tmpq = (float*)(ws + 166723584);
  float* tmpk = (float*)(ws + 166854656);
  float* tkv  = (float*)(ws + 166985728);
  float* kdvd = (float*)(ws + 166986240);
  unsigned short* Qp  = (unsigned short*)(ws + 167084544);      // 15,728,640
  unsigned short* Kp  = (unsigned short*)(ws + 182813184);      // 15,728,640 -> 198,541,824
  unsigned short* Vtg = (unsigned short*)(ws + 72351744);       // alias q0 (dead after pack)
  unsigned short* attnbf = (unsigned short*)(ws + 122683392);   // alias v0 (dead after vpackT)

  float* out = (float*)d_out;  // img [2048][3072] then enc [512][3072]

  dim3 blk(256);

  convf2b_kernel<<<6144, blk, 0, stream>>>(hs, hs_bf);
  convf2b_kernel<<<1536, blk, 0, stream>>>(enc, enc_bf);
  bokeh_down_kernel<<<8, blk, 0, stream>>>(bok, kbd, vbd, tkv);
  bokeh_up_kernel<<<96, blk, 0, stream>>>(tkv, kbu, vbu, kdvd);

  convw_kernel<<<dim3(9216, 3), blk, 0, stream>>>(Wq, Wk, Wv, w3);
  gemm3_kernel<<<1152, blk, 0, stream>>>(hs_bf, w3, bq, bk, bv, q0, k0, v0, 2048);
  convw_kernel<<<dim3(9216, 3), blk, 0, stream>>>(Waq, Wak, Wav, w3);
  gemm3_kernel<<<288, blk, 0, stream>>>(enc_bf, w3, baq, bak, bav, eq, ek, ev, 512);

  lora_down2_kernel<<<dim3(2048, 2), blk, 0, stream>>>(q0, k0, qad, kad, tmpq, tmpk);

  pack_kernel<<<dim3(SEQ / 4, HEADS, 2), blk, 0, stream>>>(
      q0, k0, eq, ek, tmpq, tmpk, qau, kau, nq, nk, naq, nak, rc, rsn, Qp, Kp);
  vpackT_kernel<<<dim3(SEQ / 64, HEADS), blk, 0, stream>>>(v0, ev, Vtg);

  attn_kernel<<<dim3(SEQ / 64, HEADS), blk, 0, stream>>>(Qp, Kp, Vtg, kdvd, attnbf);

  convw_kernel<<<dim3(9216, 2), blk, 0, stream>>>(Wo, Wao, Wao, w3);
  gemm_out_kernel<<<480, blk, 0, stream>>>(attnbf, w3, bo, bao, out);
}